// Round 13
// baseline (120.190 us; speedup 1.0000x reference)
//
#include <hip/hip_runtime.h>

// VectorQuantizer forward: out = codebook[argmin_k ||x - e_k||^2]
// R19: 4 co-resident blocks/CU. R18 (2 blocks/CU via half-staging) gave the
//      first structural win (58.4 -> 50.6 us, prediction matched): the wall
//      is the per-block serial phase chain, and independent barrier domains
//      overlap each other's phases. R19 doubles the domains: quarter-staged
//      codebook (32 KB B-packs live, 3 re-stages), 256-thr/4-wave/128-row
//      blocks, grid 1024 -> ~35 KB LDS -> 4 blocks/CU (same 16 waves/CU,
//      same 512 rows/CU, finer-grained phase interleave). Costs: codebook
//      L2 traffic 67 -> 134 MB (~+2 us chip-wide, HBM-invisible) and +4
//      barriers. Hot loop / argmin / ascending-k order / fallback /
//      epilogue byte-identical to R18. Numerics: 3-term bf16 split,
//      strict-gt first-min, exact-fp32 fallback for c-gap <= TAU/2 =>
//      committed argmins provably identical to fp32 path.

#define KC 512
#define DD 64
#define TAU 5e-4f
#define HTAU (0.5f * TAU)    // threshold in c-space (s = -2c)

typedef __attribute__((ext_vector_type(8))) short short8;
typedef __attribute__((ext_vector_type(4))) float float4v;

__device__ inline unsigned short f2bf(float f) {   // RNE bf16
    unsigned u = __float_as_uint(f);
    return (unsigned short)((u + 0x7FFF + ((u >> 16) & 1)) >> 16);
}
__device__ inline float bf2f(unsigned short b) {
    return __uint_as_float((unsigned)b << 16);
}

// Per code-tile ct (16 codes): bias (exact fp32, sequential d), et (fp32
// transposed codebook for gather/fallback), and Bh/Bl bf16 packs laid out in
// the exact 16x16x32 B-fragment order: element (lane l, j) = E[kc*32 +
// (l>>4)*8 + j][ct*16 + (l&15)].
__global__ __launch_bounds__(256) void vq_prep(const float* __restrict__ emb,
                                               float* __restrict__ et,
                                               float* __restrict__ bias,
                                               short* __restrict__ Bh,
                                               short* __restrict__ Bl) {
    __shared__ float tile[DD][17];
    const int ct = blockIdx.x;            // 0..31
    const int t  = threadIdx.x;

    {   // stage emb[d][ct*16..+16] -> tile[d][c]
        const int d = t >> 2, c0 = (t & 3) * 4;
        float4 v = *(const float4*)(emb + (size_t)d * KC + ct * 16 + c0);
        tile[d][c0 + 0] = v.x; tile[d][c0 + 1] = v.y;
        tile[d][c0 + 2] = v.z; tile[d][c0 + 3] = v.w;
    }
    __syncthreads();

    if (t < 16) {   // bias, exact sequential d-order
        float s = 0.f;
        #pragma unroll
        for (int d = 0; d < DD; ++d) { float v = tile[d][t]; s += v * v; }
        bias[ct * 16 + t] = s;
    }

    {   // et[(ct*16+c)][d0..d0+3]
        const int c = t >> 4, d0 = (t & 15) * 4;
        float4 v;
        v.x = tile[d0 + 0][c]; v.y = tile[d0 + 1][c];
        v.z = tile[d0 + 2][c]; v.w = tile[d0 + 3][c];
        *(float4*)(et + (size_t)(ct * 16 + c) * DD + d0) = v;
    }

    {   // B-fragment packs
        const int term = t >> 7;          // 0 = hi, 1 = lo
        const int kc   = (t >> 6) & 1;
        const int l    = t & 63;
        const int c    = l & 15, dq = l >> 4;
        short v8[8];
        #pragma unroll
        for (int j = 0; j < 8; ++j) {
            float f = tile[kc * 32 + dq * 8 + j][c];
            unsigned short h = f2bf(f);
            v8[j] = (short)(term == 0 ? h : f2bf(f - bf2f(h)));
        }
        short* dst = (term == 0 ? Bh : Bl) + ((size_t)(ct * 2 + kc) * 64 + l) * 8;
        *(short8*)dst = *(short8*)v8;
    }
}

// Block = 256 threads / 4 waves, covers 128 rows; wave w owns rows
// [w*32, w*32+32) in registers. Codebook swept in four quarters of 128
// codes, re-staged mid-kernel into the same 32 KB of LDS buffers ->
// ~35 KB LDS -> 4 co-resident blocks/CU whose phases overlap.
__global__ __launch_bounds__(256, 4) void vq_main(const float* __restrict__ x_in,
                                                  const short* __restrict__ Bh,
                                                  const short* __restrict__ Bl,
                                                  const float* __restrict__ bias,
                                                  const float* __restrict__ et,
                                                  float* __restrict__ out) {
    __shared__ __align__(16) short Bh_lds[8 * 2 * 64 * 8];    // 16 KB (quarter)
    __shared__ __align__(16) short Bl_lds[8 * 2 * 64 * 8];    // 16 KB (quarter)
    __shared__ float bias_s[KC];                               // 2 KB (full)
    __shared__ int   k1s[4][32];
    __shared__ float gaps[4][32];

    const int t = threadIdx.x, w = t >> 6, l = t & 63;
    const int col = l & 15, quad = l >> 4;
    const int R0 = blockIdx.x * 128;
    const int wrow0 = w * 32;

    {   // stage quarter 0 of Bh/Bl (1024 float4 each) + full bias
        const float4* srcH = (const float4*)Bh;
        const float4* srcL = (const float4*)Bl;
        float4* dstH = (float4*)Bh_lds;
        float4* dstL = (float4*)Bl_lds;
        #pragma unroll
        for (int j = 0; j < 4; ++j) {
            const int idx = t + j * 256;              // 1024 float4 per array
            dstH[idx] = srcH[idx];
            dstL[idx] = srcL[idx];
        }
        bias_s[t]       = bias[t];
        bias_s[t + 256] = bias[t + 256];
    }

    // ---- A: this wave's 32 rows -> registers, bf16 hi/lo split (done once).
    // 16x16x32 A-layout: m = lane&15, k = quad*8 + j; rt = 16-row tile 0..1.
    short8 AH[2][2], AL[2][2];
    #pragma unroll
    for (int rt = 0; rt < 2; ++rt)
        #pragma unroll
        for (int kc = 0; kc < 2; ++kc) {
            const float* p = x_in + (size_t)(R0 + wrow0 + rt * 16 + col) * DD
                           + kc * 32 + quad * 8;
            float4 xa = *(const float4*)p;
            float4 xb = *(const float4*)(p + 4);
            float f[8] = {xa.x, xa.y, xa.z, xa.w, xb.x, xb.y, xb.z, xb.w};
            short8 hi8, lo8;
            #pragma unroll
            for (int j = 0; j < 8; ++j) {
                unsigned short h = f2bf(f[j]);
                hi8[j] = (short)h;
                lo8[j] = (short)f2bf(f[j] - bf2f(h));
            }
            AH[rt][kc] = hi8;
            AL[rt][kc] = lo8;
        }
    __syncthreads();   // quarter-0 staged

    // per-(row,code-lane) running max1/max2/k in c-space (c = x.e - b/2)
    float m1[2][4], m2[2][4];
    int   kb[2][4];
    #pragma unroll
    for (int rt = 0; rt < 2; ++rt)
        #pragma unroll
        for (int r = 0; r < 4; ++r) {
            m1[rt][r] = -3.4e38f; m2[rt][r] = -3.4e38f; kb[rt][r] = 0;
        }

    #pragma unroll 1
    for (int st = 0; st < 4; ++st) {
        if (st > 0) {   // swap in the next codebook quarter (same buffers)
            __syncthreads();   // all waves done reading previous quarter
            const float4* srcH = (const float4*)Bh + st * 1024;
            const float4* srcL = (const float4*)Bl + st * 1024;
            float4* dstH = (float4*)Bh_lds;
            float4* dstL = (float4*)Bl_lds;
            #pragma unroll
            for (int j = 0; j < 4; ++j) {
                const int idx = t + j * 256;
                dstH[idx] = srcH[idx];
                dstL[idx] = srcL[idx];
            }
            __syncthreads();   // quarter staged
        }

        #pragma unroll 2
        for (int ctl = 0; ctl < 8; ++ctl) {
            short8 bh0 = *(const short8*)&Bh_lds[((ctl * 2 + 0) * 64 + l) * 8];
            short8 bh1 = *(const short8*)&Bh_lds[((ctl * 2 + 1) * 64 + l) * 8];
            short8 bl0 = *(const short8*)&Bl_lds[((ctl * 2 + 0) * 64 + l) * 8];
            short8 bl1 = *(const short8*)&Bl_lds[((ctl * 2 + 1) * 64 + l) * 8];
            const int kk = st * 128 + ctl * 16 + col;
            const float ci = -0.5f * bias_s[kk];
            #pragma unroll
            for (int rt = 0; rt < 2; ++rt) {
                float4v c = {ci, ci, ci, ci};
                c = __builtin_amdgcn_mfma_f32_16x16x32_bf16(AH[rt][0], bh0, c, 0, 0, 0);
                c = __builtin_amdgcn_mfma_f32_16x16x32_bf16(AH[rt][1], bh1, c, 0, 0, 0);
                c = __builtin_amdgcn_mfma_f32_16x16x32_bf16(AL[rt][0], bh0, c, 0, 0, 0);
                c = __builtin_amdgcn_mfma_f32_16x16x32_bf16(AL[rt][1], bh1, c, 0, 0, 0);
                c = __builtin_amdgcn_mfma_f32_16x16x32_bf16(AH[rt][0], bl0, c, 0, 0, 0);
                c = __builtin_amdgcn_mfma_f32_16x16x32_bf16(AH[rt][1], bl1, c, 0, 0, 0);
                #pragma unroll
                for (int r = 0; r < 4; ++r) {
                    float cr = c[r];
                    bool gt = cr > m1[rt][r];                // strict: first-min k
                    m2[rt][r] = fmaxf(fminf(cr, m1[rt][r]), m2[rt][r]);
                    kb[rt][r] = gt ? kk : kb[rt][r];
                    m1[rt][r] = fmaxf(m1[rt][r], cr);
                }
            }
        }
    }

    // reduce over the 16 code-lanes (once per wave); C layout: row =
    // rt*16 + quad*4 + r, col = lane&15. k1s/gaps are wave-local from here
    // on (all reads indexed [w]) -> no block barrier needed.
    #pragma unroll
    for (int rt = 0; rt < 2; ++rt)
        #pragma unroll
        for (int r = 0; r < 4; ++r) {
            float b1 = m1[rt][r], b2 = m2[rt][r];
            int   bk = kb[rt][r];
            #pragma unroll
            for (int m = 1; m <= 8; m <<= 1) {
                float o1 = __shfl_xor(b1, m, 64);
                float o2 = __shfl_xor(b2, m, 64);
                int   ok = __shfl_xor(bk, m, 64);
                float n2 = fmaxf(fmaxf(b2, o2), fminf(b1, o1));
                bool take = (o1 > b1) || (o1 == b1 && ok < bk);
                b1 = take ? o1 : b1;
                bk = take ? ok : bk;
                b2 = n2;
            }
            if (col == 0) {
                const int rowl = rt * 16 + quad * 4 + r;
                k1s[w][rowl]  = bk;
                gaps[w][rowl] = b1 - b2;     // c-space gap = s-gap / 2
            }
        }

    {   // exact fp32 fallback for near-tie rows (ballot-driven, rare).
        // Lane l scans codes [8l,8l+8) ascending; cross-lane tie-break =
        // lower k => numpy first-min semantics, independent of approx path.
        unsigned long long mask = __ballot((l < 32) && (gaps[w][l & 31] <= HTAU));
        mask &= 0xFFFFFFFFull;
        while (mask) {
            const int rr = __builtin_ctzll(mask);
            mask &= mask - 1;
            const size_t grow = (size_t)(R0 + wrow0 + rr) * DD;
            const int kbase = l * 8;
            float acc[8];
            #pragma unroll
            for (int j = 0; j < 8; ++j) acc[j] = 0.f;
            for (int d0 = 0; d0 < DD; d0 += 4) {
                float4 xv = *(const float4*)(x_in + grow + d0);
                #pragma unroll
                for (int j = 0; j < 8; ++j) {
                    float4 ev = *(const float4*)(et + (size_t)(kbase + j) * DD + d0);
                    acc[j] += xv.x * ev.x;
                    acc[j] += xv.y * ev.y;
                    acc[j] += xv.z * ev.z;
                    acc[j] += xv.w * ev.w;
                }
            }
            float4 b0 = *(const float4*)(bias + kbase);
            float4 b1v = *(const float4*)(bias + kbase + 4);
            float bb[8] = {b0.x, b0.y, b0.z, b0.w, b1v.x, b1v.y, b1v.z, b1v.w};
            float bv = 3.4e38f; int bk = 0;
            #pragma unroll
            for (int j = 0; j < 8; ++j) {
                float s = bb[j] - 2.f * acc[j];
                if (s < bv) { bv = s; bk = kbase + j; }
            }
            #pragma unroll
            for (int m = 1; m <= 32; m <<= 1) {
                float ov = __shfl_xor(bv, m, 64);
                int   ok = __shfl_xor(bk, m, 64);
                if (ov < bv || (ov == bv && ok < bk)) { bv = ov; bk = ok; }
            }
            if (l == 0) k1s[w][rr] = bk;
        }
    }

    {   // gather epilogue (per wave, its own rows): 16 lanes per row
        const int c4 = col * 4;
        #pragma unroll
        for (int i = 0; i < 8; ++i) {
            const int rowl = i * 4 + quad;
            const int bk = k1s[w][rowl];
            float4 v = *(const float4*)(et + (size_t)bk * DD + c4);
            *(float4*)(out + (size_t)(R0 + wrow0 + rowl) * DD + c4) = v;
        }
    }
}

extern "C" void kernel_launch(void* const* d_in, const int* in_sizes, int n_in,
                              void* d_out, int out_size, void* d_ws, size_t ws_size,
                              hipStream_t stream) {
    const float* x_in = (const float*)d_in[0];   // [131072, 64]
    const float* emb  = (const float*)d_in[1];   // [64, 512]
    float* out = (float*)d_out;

    float* et   = (float*)d_ws;                       // 512*64 f32 = 131072 B
    float* bias = et + KC * DD;                       // 2048 B
    short* Bh   = (short*)(bias + KC);                // 32*2*64*8 shorts = 64 KB
    short* Bl   = Bh + 32 * 2 * 64 * 8;               // 64 KB

    const int N = out_size / DD;                      // 131072 rows

    vq_prep<<<32, 256, 0, stream>>>(emb, et, bias, Bh, Bl);
    vq_main<<<N / 128, 256, 0, stream>>>(x_in, Bh, Bl, bias, et, out);
}

// Round 14
// 119.461 us; speedup vs baseline: 1.0061x; 1.0061x over previous
//
#include <hip/hip_runtime.h>

// VectorQuantizer forward: out = codebook[argmin_k ||x - e_k||^2]
// R20: async DMA codebook staging. R19 (4 blocks/CU) regressed: more
//      domains also doubled staged bytes + barriers. R18 (2 blocks/CU,
//      50.6us) is champion; its one serial re-stage (barrier -> VGPR
//      round-trip loads -> ds_write -> barrier) is exposed latency. Now:
//      quarter double-buffer with __builtin_amdgcn_global_load_lds
//      (16B/lane, wave-uniform base + lane*16 -- our staging layout
//      exactly): quarter q+1 streams L2->LDS into buf[(q+1)&1] WHILE
//      quarter q is swept from buf[q&1]; the vmcnt drain at each
//      __syncthreads lands behind a full quarter-sweep of cover. Same
//      total staged bytes, ~68 KB LDS, same 2 blocks/CU. Sweep / argmin /
//      ascending-k / fallback / epilogue byte-identical to R18. Numerics:
//      3-term bf16 split, strict-gt first-min, exact-fp32 fallback for
//      c-gap <= TAU/2 => committed argmins provably identical to fp32.

#define KC 512
#define DD 64
#define TAU 5e-4f
#define HTAU (0.5f * TAU)    // threshold in c-space (s = -2c)

typedef __attribute__((ext_vector_type(8))) short short8;
typedef __attribute__((ext_vector_type(4))) float float4v;

__device__ inline unsigned short f2bf(float f) {   // RNE bf16
    unsigned u = __float_as_uint(f);
    return (unsigned short)((u + 0x7FFF + ((u >> 16) & 1)) >> 16);
}
__device__ inline float bf2f(unsigned short b) {
    return __uint_as_float((unsigned)b << 16);
}

__device__ inline void gload16(const void* gsrc, void* ldst) {
    __builtin_amdgcn_global_load_lds(
        (const __attribute__((address_space(1))) void*)gsrc,
        (__attribute__((address_space(3))) void*)ldst, 16, 0, 0);
}

// Per code-tile ct (16 codes): bias (exact fp32, sequential d), et (fp32
// transposed codebook for gather/fallback), and Bh/Bl bf16 packs laid out in
// the exact 16x16x32 B-fragment order: element (lane l, j) = E[kc*32 +
// (l>>4)*8 + j][ct*16 + (l&15)].
__global__ __launch_bounds__(256) void vq_prep(const float* __restrict__ emb,
                                               float* __restrict__ et,
                                               float* __restrict__ bias,
                                               short* __restrict__ Bh,
                                               short* __restrict__ Bl) {
    __shared__ float tile[DD][17];
    const int ct = blockIdx.x;            // 0..31
    const int t  = threadIdx.x;

    {   // stage emb[d][ct*16..+16] -> tile[d][c]
        const int d = t >> 2, c0 = (t & 3) * 4;
        float4 v = *(const float4*)(emb + (size_t)d * KC + ct * 16 + c0);
        tile[d][c0 + 0] = v.x; tile[d][c0 + 1] = v.y;
        tile[d][c0 + 2] = v.z; tile[d][c0 + 3] = v.w;
    }
    __syncthreads();

    if (t < 16) {   // bias, exact sequential d-order
        float s = 0.f;
        #pragma unroll
        for (int d = 0; d < DD; ++d) { float v = tile[d][t]; s += v * v; }
        bias[ct * 16 + t] = s;
    }

    {   // et[(ct*16+c)][d0..d0+3]
        const int c = t >> 4, d0 = (t & 15) * 4;
        float4 v;
        v.x = tile[d0 + 0][c]; v.y = tile[d0 + 1][c];
        v.z = tile[d0 + 2][c]; v.w = tile[d0 + 3][c];
        *(float4*)(et + (size_t)(ct * 16 + c) * DD + d0) = v;
    }

    {   // B-fragment packs
        const int term = t >> 7;          // 0 = hi, 1 = lo
        const int kc   = (t >> 6) & 1;
        const int l    = t & 63;
        const int c    = l & 15, dq = l >> 4;
        short v8[8];
        #pragma unroll
        for (int j = 0; j < 8; ++j) {
            float f = tile[kc * 32 + dq * 8 + j][c];
            unsigned short h = f2bf(f);
            v8[j] = (short)(term == 0 ? h : f2bf(f - bf2f(h)));
        }
        short* dst = (term == 0 ? Bh : Bl) + ((size_t)(ct * 2 + kc) * 64 + l) * 8;
        *(short8*)dst = *(short8*)v8;
    }
}

// Block = 512 threads / 8 waves, covers 256 rows; wave w owns rows
// [w*32, w*32+32) in registers. Codebook swept in four quarters of 128
// codes, double-buffered in LDS: quarter q+1 DMAs in (global_load_lds)
// while quarter q is swept. ~68 KB LDS -> 2 co-resident blocks/CU.
__global__ __launch_bounds__(512, 4) void vq_main(const float* __restrict__ x_in,
                                                  const short* __restrict__ Bh,
                                                  const short* __restrict__ Bl,
                                                  const float* __restrict__ bias,
                                                  const float* __restrict__ et,
                                                  float* __restrict__ out) {
    __shared__ __align__(16) short Bh_lds[2][8 * 2 * 64 * 8];   // 2 x 16 KB
    __shared__ __align__(16) short Bl_lds[2][8 * 2 * 64 * 8];   // 2 x 16 KB
    __shared__ float bias_s[KC];                                 // 2 KB
    __shared__ int   k1s[8][32];
    __shared__ float gaps[8][32];

    const int t = threadIdx.x, w = t >> 6, l = t & 63;
    const int col = l & 15, quad = l >> 4;
    const int R0 = blockIdx.x * 256;
    const int wrow0 = w * 32;

    {   // DMA quarter 0 -> buf 0 (async; drains at the prologue barrier)
        const float4* srcH = (const float4*)Bh;
        const float4* srcL = (const float4*)Bl;
        #pragma unroll
        for (int j = 0; j < 2; ++j) {
            const int idx = t + j * 512;              // 1024 float4 per array
            gload16(srcH + idx, &Bh_lds[0][idx * 8]);
            gload16(srcL + idx, &Bl_lds[0][idx * 8]);
        }
        bias_s[t] = bias[t];
    }

    // ---- A: this wave's 32 rows -> registers, bf16 hi/lo split (done once;
    // overlaps the quarter-0 DMA). 16x16x32 A-layout: m = lane&15,
    // k = quad*8 + j; rt = 16-row tile 0..1.
    short8 AH[2][2], AL[2][2];
    #pragma unroll
    for (int rt = 0; rt < 2; ++rt)
        #pragma unroll
        for (int kc = 0; kc < 2; ++kc) {
            const float* p = x_in + (size_t)(R0 + wrow0 + rt * 16 + col) * DD
                           + kc * 32 + quad * 8;
            float4 xa = *(const float4*)p;
            float4 xb = *(const float4*)(p + 4);
            float f[8] = {xa.x, xa.y, xa.z, xa.w, xb.x, xb.y, xb.z, xb.w};
            short8 hi8, lo8;
            #pragma unroll
            for (int j = 0; j < 8; ++j) {
                unsigned short h = f2bf(f[j]);
                hi8[j] = (short)h;
                lo8[j] = (short)f2bf(f[j] - bf2f(h));
            }
            AH[rt][kc] = hi8;
            AL[rt][kc] = lo8;
        }
    __syncthreads();   // quarter-0 DMA drained + staged

    // per-(row,code-lane) running max1/max2/k in c-space (c = x.e - b/2)
    float m1[2][4], m2[2][4];
    int   kb[2][4];
    #pragma unroll
    for (int rt = 0; rt < 2; ++rt)
        #pragma unroll
        for (int r = 0; r < 4; ++r) {
            m1[rt][r] = -3.4e38f; m2[rt][r] = -3.4e38f; kb[rt][r] = 0;
        }

    #pragma unroll 1
    for (int st = 0; st < 4; ++st) {
        const int cur = st & 1;

        if (st < 3) {   // async-prefetch next quarter into the other buffer
            const float4* srcH = (const float4*)Bh + (st + 1) * 1024;
            const float4* srcL = (const float4*)Bl + (st + 1) * 1024;
            short* dH = Bh_lds[cur ^ 1];
            short* dL = Bl_lds[cur ^ 1];
            #pragma unroll
            for (int j = 0; j < 2; ++j) {
                const int idx = t + j * 512;
                gload16(srcH + idx, dH + idx * 8);
                gload16(srcL + idx, dL + idx * 8);
            }
        }

        const short* BhS = Bh_lds[cur];
        const short* BlS = Bl_lds[cur];
        #pragma unroll 2
        for (int ctl = 0; ctl < 8; ++ctl) {
            short8 bh0 = *(const short8*)&BhS[((ctl * 2 + 0) * 64 + l) * 8];
            short8 bh1 = *(const short8*)&BhS[((ctl * 2 + 1) * 64 + l) * 8];
            short8 bl0 = *(const short8*)&BlS[((ctl * 2 + 0) * 64 + l) * 8];
            short8 bl1 = *(const short8*)&BlS[((ctl * 2 + 1) * 64 + l) * 8];
            const int kk = st * 128 + ctl * 16 + col;
            const float ci = -0.5f * bias_s[kk];
            #pragma unroll
            for (int rt = 0; rt < 2; ++rt) {
                float4v c = {ci, ci, ci, ci};
                c = __builtin_amdgcn_mfma_f32_16x16x32_bf16(AH[rt][0], bh0, c, 0, 0, 0);
                c = __builtin_amdgcn_mfma_f32_16x16x32_bf16(AH[rt][1], bh1, c, 0, 0, 0);
                c = __builtin_amdgcn_mfma_f32_16x16x32_bf16(AL[rt][0], bh0, c, 0, 0, 0);
                c = __builtin_amdgcn_mfma_f32_16x16x32_bf16(AL[rt][1], bh1, c, 0, 0, 0);
                c = __builtin_amdgcn_mfma_f32_16x16x32_bf16(AH[rt][0], bl0, c, 0, 0, 0);
                c = __builtin_amdgcn_mfma_f32_16x16x32_bf16(AH[rt][1], bl1, c, 0, 0, 0);
                #pragma unroll
                for (int r = 0; r < 4; ++r) {
                    float cr = c[r];
                    bool gt = cr > m1[rt][r];                // strict: first-min k
                    m2[rt][r] = fmaxf(fminf(cr, m1[rt][r]), m2[rt][r]);
                    kb[rt][r] = gt ? kk : kb[rt][r];
                    m1[rt][r] = fmaxf(m1[rt][r], cr);
                }
            }
        }

        if (st < 3) __syncthreads();   // drains next-quarter DMA; reads done
    }

    // reduce over the 16 code-lanes (once per wave); C layout: row =
    // rt*16 + quad*4 + r, col = lane&15. k1s/gaps are wave-local from here
    // on (all reads indexed [w]) -> no block barrier needed.
    #pragma unroll
    for (int rt = 0; rt < 2; ++rt)
        #pragma unroll
        for (int r = 0; r < 4; ++r) {
            float b1 = m1[rt][r], b2 = m2[rt][r];
            int   bk = kb[rt][r];
            #pragma unroll
            for (int m = 1; m <= 8; m <<= 1) {
                float o1 = __shfl_xor(b1, m, 64);
                float o2 = __shfl_xor(b2, m, 64);
                int   ok = __shfl_xor(bk, m, 64);
                float n2 = fmaxf(fmaxf(b2, o2), fminf(b1, o1));
                bool take = (o1 > b1) || (o1 == b1 && ok < bk);
                b1 = take ? o1 : b1;
                bk = take ? ok : bk;
                b2 = n2;
            }
            if (col == 0) {
                const int rowl = rt * 16 + quad * 4 + r;
                k1s[w][rowl]  = bk;
                gaps[w][rowl] = b1 - b2;     // c-space gap = s-gap / 2
            }
        }

    {   // exact fp32 fallback for near-tie rows (ballot-driven, rare).
        // Lane l scans codes [8l,8l+8) ascending; cross-lane tie-break =
        // lower k => numpy first-min semantics, independent of approx path.
        unsigned long long mask = __ballot((l < 32) && (gaps[w][l & 31] <= HTAU));
        mask &= 0xFFFFFFFFull;
        while (mask) {
            const int rr = __builtin_ctzll(mask);
            mask &= mask - 1;
            const size_t grow = (size_t)(R0 + wrow0 + rr) * DD;
            const int kbase = l * 8;
            float acc[8];
            #pragma unroll
            for (int j = 0; j < 8; ++j) acc[j] = 0.f;
            for (int d0 = 0; d0 < DD; d0 += 4) {
                float4 xv = *(const float4*)(x_in + grow + d0);
                #pragma unroll
                for (int j = 0; j < 8; ++j) {
                    float4 ev = *(const float4*)(et + (size_t)(kbase + j) * DD + d0);
                    acc[j] += xv.x * ev.x;
                    acc[j] += xv.y * ev.y;
                    acc[j] += xv.z * ev.z;
                    acc[j] += xv.w * ev.w;
                }
            }
            float4 b0 = *(const float4*)(bias + kbase);
            float4 b1v = *(const float4*)(bias + kbase + 4);
            float bb[8] = {b0.x, b0.y, b0.z, b0.w, b1v.x, b1v.y, b1v.z, b1v.w};
            float bv = 3.4e38f; int bk = 0;
            #pragma unroll
            for (int j = 0; j < 8; ++j) {
                float s = bb[j] - 2.f * acc[j];
                if (s < bv) { bv = s; bk = kbase + j; }
            }
            #pragma unroll
            for (int m = 1; m <= 32; m <<= 1) {
                float ov = __shfl_xor(bv, m, 64);
                int   ok = __shfl_xor(bk, m, 64);
                if (ov < bv || (ov == bv && ok < bk)) { bv = ov; bk = ok; }
            }
            if (l == 0) k1s[w][rr] = bk;
        }
    }

    {   // gather epilogue (per wave, its own rows): 16 lanes per row
        const int c4 = col * 4;
        #pragma unroll
        for (int i = 0; i < 8; ++i) {
            const int rowl = i * 4 + quad;
            const int bk = k1s[w][rowl];
            float4 v = *(const float4*)(et + (size_t)bk * DD + c4);
            *(float4*)(out + (size_t)(R0 + wrow0 + rowl) * DD + c4) = v;
        }
    }
}

extern "C" void kernel_launch(void* const* d_in, const int* in_sizes, int n_in,
                              void* d_out, int out_size, void* d_ws, size_t ws_size,
                              hipStream_t stream) {
    const float* x_in = (const float*)d_in[0];   // [131072, 64]
    const float* emb  = (const float*)d_in[1];   // [64, 512]
    float* out = (float*)d_out;

    float* et   = (float*)d_ws;                       // 512*64 f32 = 131072 B
    float* bias = et + KC * DD;                       // 2048 B
    short* Bh   = (short*)(bias + KC);                // 32*2*64*8 shorts = 64 KB
    short* Bl   = Bh + 32 * 2 * 64 * 8;               // 64 KB

    const int N = out_size / DD;                      // 131072 rows

    vq_prep<<<32, 256, 0, stream>>>(emb, et, bias, Bh, Bl);
    vq_main<<<N / 256, 512, 0, stream>>>(x_in, Bh, Bl, bias, et, out);
}